// Round 12
// baseline (514.989 us; speedup 1.0000x reference)
//
#include <hip/hip_runtime.h>
#include <hip/hip_bf16.h>
#include <math.h>

#define NN 50000
#define EE 1600000
#define KK 30000
#define RTILE 1088   // 17 * 64
#define NTILES 48    // 48*1088 = 52224 >= NN
#define CHUNK 16384
#define GBLK 98      // ceil(EE/CHUNK)
#define BKT 391      // ceil(NN/128)
#define CMAX 6144    // bucket CSR staging cap (avg 4092, sigma 64)

typedef __attribute__((ext_vector_type(8))) short bf16x8;  // 8 bf16 = 4 VGPR (MFMA A/B frag)
typedef __attribute__((ext_vector_type(4))) float f32x4;   // MFMA C/D frag

__device__ __forceinline__ float gelu_f(float v) {
  return 0.5f * v * (1.0f + erff(v * 0.70710678118654752440f));
}

__device__ __forceinline__ unsigned short f2bf(float x) {
  __hip_bfloat16 h = __float2bfloat16(x);   // RNE
  return *(unsigned short*)&h;
}

__device__ __forceinline__ float bf2f(unsigned u16) {  // low 16 bits hold bf16
  return __uint_as_float(u16 << 16);
}

// ---------------- generic multi-block exclusive scan (used by radix digit scan) ----------------
__global__ __launch_bounds__(1024) void k_scanA(const unsigned* __restrict__ in, unsigned* __restrict__ out,
                                                unsigned* __restrict__ bsum, int n) {
  __shared__ unsigned sh[1024];
  int t = threadIdx.x;
  int i = blockIdx.x * 1024 + t;
  unsigned v = (i < n) ? in[i] : 0u;
  sh[t] = v;
  __syncthreads();
  for (int ofs = 1; ofs < 1024; ofs <<= 1) {
    unsigned add = (t >= ofs) ? sh[t - ofs] : 0u;
    __syncthreads();
    sh[t] += add;
    __syncthreads();
  }
  if (i < n) out[i] = sh[t] - v;  // exclusive
  if (t == 1023) bsum[blockIdx.x] = sh[1023];
}

__global__ __launch_bounds__(1024) void k_scanB(unsigned* __restrict__ bsum, int nb) {
  __shared__ unsigned sh[1024];
  int t = threadIdx.x;
  unsigned v = (t < nb) ? bsum[t] : 0u;
  sh[t] = v;
  __syncthreads();
  for (int ofs = 1; ofs < 1024; ofs <<= 1) {
    unsigned add = (t >= ofs) ? sh[t - ofs] : 0u;
    __syncthreads();
    sh[t] += add;
    __syncthreads();
  }
  if (t < nb) bsum[t] = sh[t] - v;  // exclusive block offsets
}

__global__ __launch_bounds__(1024) void k_scanC(unsigned* __restrict__ out, const unsigned* __restrict__ bsum, int n) {
  int i = blockIdx.x * 1024 + threadIdx.x;
  if (i < n) out[i] += bsum[blockIdx.x];  // bsum[0]==0
}

// ---------------- binned CSR fill, phase A: chunk-local bucket sort (all-coalesced global I/O) ----------------
__global__ __launch_bounds__(512) void k_binA(const int* __restrict__ src, const int* __restrict__ dst,
                                              unsigned* __restrict__ chunkEdges, int* __restrict__ chunkBase) {
  __shared__ int hist[BKT];
  __shared__ int scanb[512];
  __shared__ unsigned buf[CHUNK];
  int t = threadIdx.x, g = blockIdx.x;
  int e0 = g * CHUNK;
  int n = EE - e0; if (n > CHUNK) n = CHUNK;
  for (int i = t; i < BKT; i += 512) hist[i] = 0;
  __syncthreads();
  for (int i = t; i < n; i += 512) atomicAdd(&hist[dst[e0 + i] >> 7], 1);
  __syncthreads();
  int v = (t < BKT) ? hist[t] : 0;
  scanb[t] = v;
  __syncthreads();
  for (int ofs = 1; ofs < 512; ofs <<= 1) {
    int a = (t >= ofs) ? scanb[t - ofs] : 0;
    __syncthreads();
    scanb[t] += a;
    __syncthreads();
  }
  if (t < BKT) {
    scanb[t] -= v;
    chunkBase[g * (BKT + 1) + t] = scanb[t];
    hist[t] = 0;  // reuse as running counters
  }
  if (t == 0) chunkBase[g * (BKT + 1) + BKT] = n;
  __syncthreads();
  for (int i = t; i < n; i += 512) {
    int d = dst[e0 + i], s = src[e0 + i];
    int b = d >> 7;
    int pos = scanb[b] + atomicAdd(&hist[b], 1);
    buf[pos] = ((unsigned)(d & 127) << 16) | (unsigned)s;
  }
  __syncthreads();
  for (int i = t; i < n; i += 512) chunkEdges[e0 + i] = buf[i];
}

// ---------------- bucket totals + exclusive scan -> bktBase ----------------
__global__ __launch_bounds__(512) void k_bktsum(const int* __restrict__ chunkBase, unsigned* __restrict__ bktBase) {
  __shared__ unsigned sh[512];
  int t = threadIdx.x;
  unsigned s = 0;
  if (t < BKT) {
    for (int g = 0; g < GBLK; g++)
      s += (unsigned)(chunkBase[g * (BKT + 1) + t + 1] - chunkBase[g * (BKT + 1) + t]);
  }
  sh[t] = s;
  __syncthreads();
  for (int ofs = 1; ofs < 512; ofs <<= 1) {
    unsigned a = (t >= ofs) ? sh[t - ofs] : 0u;
    __syncthreads();
    sh[t] += a;
    __syncthreads();
  }
  if (t < BKT) bktBase[t] = sh[t] - s;  // exclusive
  if (t == 0) bktBase[BKT] = EE;
}

// ---------------- binned CSR fill, phase C: gather + LDS count/scan -> rowp + csr ----------------
__global__ __launch_bounds__(256) void k_binC(const unsigned* __restrict__ chunkEdges, const int* __restrict__ chunkBase,
                                              const unsigned* __restrict__ bktBase,
                                              int* __restrict__ rowp, int* __restrict__ csr) {
  __shared__ int segS[GBLK + 1];
  __shared__ int cnt[128];
  __shared__ int loc[128];
  __shared__ unsigned eBuf[CMAX];
  __shared__ int csrB[CMAX];
  int t = threadIdx.x, b = blockIdx.x;
  int n0 = b << 7;
  int nb = NN - n0; if (nb > 128) nb = 128;
  if (t < GBLK) segS[t] = chunkBase[t * (BKT + 1) + b + 1] - chunkBase[t * (BKT + 1) + b];
  if (t < 128) cnt[t] = 0;
  __syncthreads();
  if (t == 0) {
    int run = 0;
    for (int g = 0; g < GBLK; g++) { int L = segS[g]; segS[g] = run; run += L; }
    segS[GBLK] = run;
  }
  __syncthreads();
  int total = segS[GBLK];
  for (int i = t; i < total; i += 256) {
    int lo = 0, hi = GBLK - 1;
    while (lo < hi) { int mid = (lo + hi + 1) >> 1; if (segS[mid] <= i) lo = mid; else hi = mid - 1; }
    int off = chunkBase[lo * (BKT + 1) + b] + (i - segS[lo]);
    unsigned v = chunkEdges[lo * CHUNK + off];
    if (i < CMAX) eBuf[i] = v;
    atomicAdd(&cnt[v >> 16], 1);
  }
  __syncthreads();
  if (t < 128) loc[t] = cnt[t];
  __syncthreads();
  for (int ofs = 1; ofs < 128; ofs <<= 1) {
    int a = (t < 128 && t >= ofs) ? loc[t - ofs] : 0;
    __syncthreads();
    if (t < 128) loc[t] += a;
    __syncthreads();
  }
  if (t < 128) loc[t] -= cnt[t];  // exclusive local offsets
  __syncthreads();
  int base = (int)bktBase[b];
  if (t < nb) rowp[n0 + t] = base + loc[t];
  if (b == BKT - 1 && t == 0) rowp[NN] = base + total;  // == EE
  if (t < 128) cnt[t] = 0;  // reuse as running counters
  __syncthreads();
  for (int i = t; i < total && i < CMAX; i += 256) {
    unsigned v = eBuf[i];
    int d = (int)(v >> 16);
    int pos = loc[d] + atomicAdd(&cnt[d], 1);
    if (pos < CMAX) csrB[pos] = (int)(v & 0xFFFFu);
  }
  __syncthreads();
  for (int i = t; i < total && i < CMAX; i += 256) csr[base + i] = csrB[i];
}

// ---------------- dense input layer: h0 = gelu(x @ wd_root + b) ----------------
__global__ __launch_bounds__(256) void k_dense(const float* __restrict__ x, const float* __restrict__ w,
                                               const float* __restrict__ b, float* __restrict__ h0) {
  __shared__ float ws[260];
  int t = threadIdx.x;
  ws[t] = w[t];                    // w is 64*4 = 256
  if (t < 4) ws[256 + t] = b[t];
  __syncthreads();
  int n = blockIdx.x * 256 + t;
  if (n >= NN) return;
  float acc0 = ws[256], acc1 = ws[257], acc2 = ws[258], acc3 = ws[259];
  const float4* xr = (const float4*)(x + (size_t)n * 64);
#pragma unroll
  for (int k4 = 0; k4 < 16; k4++) {
    float4 v = xr[k4];
    const float* wk = &ws[k4 * 16];
    acc0 += v.x * wk[0];  acc1 += v.x * wk[1];  acc2 += v.x * wk[2];  acc3 += v.x * wk[3];
    acc0 += v.y * wk[4];  acc1 += v.y * wk[5];  acc2 += v.y * wk[6];  acc3 += v.y * wk[7];
    acc0 += v.z * wk[8];  acc1 += v.z * wk[9];  acc2 += v.z * wk[10]; acc3 += v.z * wk[11];
    acc0 += v.w * wk[12]; acc1 += v.w * wk[13]; acc2 += v.w * wk[14]; acc3 += v.w * wk[15];
  }
  float4 o;
  o.x = gelu_f(acc0); o.y = gelu_f(acc1); o.z = gelu_f(acc2); o.w = gelu_f(acc3);
  ((float4*)h0)[n] = o;
}

// ---------------- pull aggregation, unroll-4: agg[n][:] = sum_{s in in(n)} h[s][:] ----------------
template <int TPN>
__global__ __launch_bounds__(256) void k_agg(const float* __restrict__ h, const int* __restrict__ rowp,
                                             const int* __restrict__ csr, float* __restrict__ agg) {
  long gt = (long)blockIdx.x * 256 + threadIdx.x;
  int n = (int)(gt / TPN), lane = (int)(gt % TPN);
  if (n >= NN) return;
  int beg = rowp[n], end = rowp[n + 1];
  const float4* hv = (const float4*)h;
  float4 a0 = make_float4(0.f, 0.f, 0.f, 0.f), a1 = a0, a2 = a0, a3 = a0;
  int e = beg;
  for (; e + 4 <= end; e += 4) {
    int s0 = csr[e], s1 = csr[e + 1], s2 = csr[e + 2], s3 = csr[e + 3];
    float4 v0 = hv[(size_t)s0 * TPN + lane];
    float4 v1 = hv[(size_t)s1 * TPN + lane];
    float4 v2 = hv[(size_t)s2 * TPN + lane];
    float4 v3 = hv[(size_t)s3 * TPN + lane];
    a0.x += v0.x; a0.y += v0.y; a0.z += v0.z; a0.w += v0.w;
    a1.x += v1.x; a1.y += v1.y; a1.z += v1.z; a1.w += v1.w;
    a2.x += v2.x; a2.y += v2.y; a2.z += v2.z; a2.w += v2.w;
    a3.x += v3.x; a3.y += v3.y; a3.z += v3.z; a3.w += v3.w;
  }
  for (; e < end; e++) {
    int s = csr[e];
    float4 v = hv[(size_t)s * TPN + lane];
    a0.x += v.x; a0.y += v.y; a0.z += v.z; a0.w += v.w;
  }
  float4 acc;
  acc.x = (a0.x + a1.x) + (a2.x + a3.x);
  acc.y = (a0.y + a1.y) + (a2.y + a3.y);
  acc.z = (a0.z + a1.z) + (a2.z + a3.z);
  acc.w = (a0.w + a1.w) + (a2.w + a3.w);
  ((float4*)agg)[(size_t)n * TPN + lane] = acc;
}

// ---------------- conv0 GEMM (DIN=4 -> DOUT=32) ----------------
__global__ __launch_bounds__(256) void k_gemm0(const float* __restrict__ agg0, const float* __restrict__ h0,
                                               const float* __restrict__ wrel, const float* __restrict__ wroot,
                                               const float* __restrict__ bias, float* __restrict__ h1) {
  __shared__ float ws[288];
  int t = threadIdx.x;
  if (t < 128) { ws[t] = wrel[t]; ws[128 + t] = wroot[t]; }
  if (t < 32) ws[256 + t] = bias[t];
  __syncthreads();
  int gt = blockIdx.x * 256 + t;
  int n = gt >> 5, j = gt & 31;
  if (n >= NN) return;
  float4 a = ((const float4*)agg0)[n];
  float4 h = ((const float4*)h0)[n];
  float acc = ws[256 + j];
  acc += a.x * ws[j]        + a.y * ws[32 + j]  + a.z * ws[64 + j]  + a.w * ws[96 + j];
  acc += h.x * ws[128 + j]  + h.y * ws[160 + j] + h.z * ws[192 + j] + h.w * ws[224 + j];
  h1[(size_t)n * 32 + j] = gelu_f(acc);
}

// ---------------- weight pre-transpose+convert: W16T[col][k] bf16, k in [0,2*DIN) ----------------
template <int DIN, int DOUT>
__global__ __launch_bounds__(256) void k_wcvtT(const float* __restrict__ wrel, const float* __restrict__ wroot,
                                               unsigned short* __restrict__ W16T) {
  constexpr int K = 2 * DIN;
  int idx = blockIdx.x * 256 + threadIdx.x;  // DOUT*K total
  int col = idx / K, k = idx % K;
  float v = (k < DIN) ? wrel[(size_t)k * DOUT + col] : wroot[(size_t)(k - DIN) * DOUT + col];
  W16T[(size_t)col * K + k] = f2bf(v);
}

// ---------------- MFMA conv GEMM: Cout = gelu(bf16([agg|h]) @ W + b), fp32 accum ----------------
// Block 256 = 4 waves; tile 64 rows x DOUT cols; wave wv owns cols [wv*DOUT/4, ...+DOUT/4).
// Whole W^T (bf16, padded stride K+8) stays in LDS; A panel converted fp32->bf16 per K-step.
template <int DIN, int DOUT>
__global__ __launch_bounds__(256) void k_gemmM(const float* __restrict__ Ag, const float* __restrict__ Hp,
                                               const unsigned short* __restrict__ W16T,
                                               const float* __restrict__ bias, float* __restrict__ Cout, int R) {
  constexpr int K = 2 * DIN;
  constexpr int NF = DOUT / 64;   // 16-col frags per wave
  constexpr int WSTR = K + 8;     // pad -> <=2-way bank aliasing (free)
  __shared__ unsigned short Al[64][40];
  __shared__ unsigned short Wl[DOUT][WSTR];
  int t = threadIdx.x;
  int wv = t >> 6, l = t & 63;
  int n0 = blockIdx.x * 64;
  // stage whole W^T
  for (int i = t; i < DOUT * (K / 8); i += 256) {
    int col = i / (K / 8), ks = i % (K / 8);
    uint4 v = *(const uint4*)&W16T[(size_t)col * K + ks * 8];
    *(uint4*)&Wl[col][ks * 8] = v;
  }
  f32x4 acc[4][NF];
#pragma unroll
  for (int m = 0; m < 4; m++)
#pragma unroll
    for (int n = 0; n < NF; n++) acc[m][n] = (f32x4){0.f, 0.f, 0.f, 0.f};
  int row = t >> 2, koff = (t & 3) * 8;
  int gr = n0 + row;
  for (int kc = 0; kc < K; kc += 32) {
    const float* srcp = (kc < DIN) ? Ag : Hp;
    int kbase = (kc < DIN) ? kc : (kc - DIN);
    float4 v0 = make_float4(0.f, 0.f, 0.f, 0.f), v1 = v0;
    if (gr < R) {
      const float* rp = srcp + (size_t)gr * DIN + kbase + koff;
      v0 = *(const float4*)rp;
      v1 = *(const float4*)(rp + 4);
    }
    uint4 p;
    p.x = (unsigned)f2bf(v0.x) | ((unsigned)f2bf(v0.y) << 16);
    p.y = (unsigned)f2bf(v0.z) | ((unsigned)f2bf(v0.w) << 16);
    p.z = (unsigned)f2bf(v1.x) | ((unsigned)f2bf(v1.y) << 16);
    p.w = (unsigned)f2bf(v1.z) | ((unsigned)f2bf(v1.w) << 16);
    *(uint4*)&Al[row][koff] = p;
    __syncthreads();
    int kf = (l >> 4) * 8;
    bf16x8 a[4], b[NF];
#pragma unroll
    for (int m = 0; m < 4; m++) a[m] = *(const bf16x8*)&Al[16 * m + (l & 15)][kf];
#pragma unroll
    for (int n = 0; n < NF; n++) b[n] = *(const bf16x8*)&Wl[wv * (DOUT / 4) + 16 * n + (l & 15)][kc + kf];  // FIX: +kc
#pragma unroll
    for (int m = 0; m < 4; m++)
#pragma unroll
      for (int n = 0; n < NF; n++)
        acc[m][n] = __builtin_amdgcn_mfma_f32_16x16x32_bf16(a[m], b[n], acc[m][n], 0, 0, 0);
    __syncthreads();
  }
  // epilogue: row = n0 + 16m + (l>>4)*4 + j; col = wv*(DOUT/4) + 16n + (l&15)
  int rb = (l >> 4) * 4;
#pragma unroll
  for (int n = 0; n < NF; n++) {
    int col = wv * (DOUT / 4) + 16 * n + (l & 15);
    float bs = bias[col];
#pragma unroll
    for (int m = 0; m < 4; m++) {
#pragma unroll
      for (int j = 0; j < 4; j++) {
        int r = n0 + 16 * m + rb + j;
        if (r < R) Cout[(size_t)r * DOUT + col] = gelu_f(acc[m][n][j] + bs);
      }
    }
  }
}

// ---------------- score = tanh(h3 . p / ||p||); key + fused pass-1 histogram ----------------
__global__ __launch_bounds__(256) void k_score(const float* __restrict__ h3, const float* __restrict__ p,
                                               float* __restrict__ score, unsigned* __restrict__ skey,
                                               unsigned* __restrict__ hist) {
  __shared__ float red[256];
  int t = threadIdx.x;
  float pv = 0.f;
  if (t < 128) { float q = p[t]; pv = q * q; }
  red[t] = pv;
  __syncthreads();
  for (int s = 128; s > 0; s >>= 1) { if (t < s) red[t] += red[t + s]; __syncthreads(); }
  float pinv = rsqrtf(red[0]);
  int n = blockIdx.x * 8 + (t >> 5);
  int lane = t & 31;
  if (n >= NN) return;
  float4 hv = ((const float4*)(h3 + (size_t)n * 128))[lane];
  float4 pw = ((const float4*)p)[lane];
  float d = hv.x * pw.x + hv.y * pw.y + hv.z * pw.z + hv.w * pw.w;
  for (int o = 16; o > 0; o >>= 1) d += __shfl_xor(d, o, 32);
  if (lane == 0) {
    float sc = tanhf(d * pinv);
    score[n] = sc;
    unsigned bits = __float_as_uint(sc);
    unsigned mono = (bits & 0x80000000u) ? ~bits : (bits | 0x80000000u);
    unsigned sk = ~mono;  // ascending key == descending score; stable sort -> ties by index
    skey[n] = sk;
    atomicAdd(&hist[(size_t)(n / RTILE) * 65536 + (sk & 0xFFFFu)], 1u);  // radix pass-1 hist
  }
}

// ---------------- radix sort (2 x 16-bit passes, stable) ----------------
template <int SHIFT>
__global__ __launch_bounds__(256) void k_rhist(const unsigned* __restrict__ keyIn, unsigned* __restrict__ histMat) {
  int gid = blockIdx.x * 256 + threadIdx.x;
  if (gid < NN) {
    unsigned d = (keyIn[gid] >> SHIFT) & 0xFFFFu;
    int tile = gid / RTILE;
    atomicAdd(&histMat[(size_t)tile * 65536 + d], 1u);
  }
}

__global__ __launch_bounds__(256) void k_rtileprefix(unsigned* __restrict__ histMat, unsigned* __restrict__ total) {
  int d = blockIdx.x * 256 + threadIdx.x;  // 65536 threads
  unsigned run = 0;
  for (int tl = 0; tl < NTILES; tl++) {
    size_t ix = (size_t)tl * 65536 + d;
    unsigned v = histMat[ix];
    histMat[ix] = run;
    run += v;
  }
  total[d] = run;
}

// One wave per block; ballot-based stable scatter, no LDS. Pass 1: writes key+id.
template <int SHIFT, bool FIRST>
__global__ __launch_bounds__(64) void k_rscatter(const unsigned* __restrict__ keyIn, const unsigned* __restrict__ idIn,
                                                 unsigned* __restrict__ histMat, const unsigned* __restrict__ base,
                                                 unsigned* __restrict__ keyOut, unsigned* __restrict__ idOut) {
  int t = threadIdx.x;
  int tile = blockIdx.x;
  for (int c = 0; c < RTILE / 64; c++) {
    int idx = tile * RTILE + c * 64 + t;
    int valid = idx < NN;
    unsigned key = 0u, id = 0u;
    if (valid) {
      key = keyIn[idx];
      id = FIRST ? (unsigned)idx : idIn[idx];
    }
    unsigned d = (key >> SHIFT) & 0xFFFFu;
    unsigned long long same = __ballot(valid != 0);
    if (!valid) same = ~same;
#pragma unroll
    for (int b = 0; b < 16; b++) {
      unsigned long long bb = __ballot((int)((d >> b) & 1u));
      same &= ((d >> b) & 1u) ? bb : ~bb;
    }
    unsigned long long lower = (t == 0) ? 0ull : (same << (64 - t) >> (64 - t));  // bits [0,t)
    unsigned intrar = (unsigned)__popcll(lower);
    unsigned total = (unsigned)__popcll(same);
    int leader = (int)(__ffsll((long long)same) - 1);
    unsigned old = 0u;
    if (valid && t == leader) old = atomicAdd(&histMat[(size_t)tile * 65536 + d], total);
    unsigned basec = (unsigned)__shfl((int)old, leader, 64);
    if (valid) {
      unsigned pos = base[d] + basec + intrar;
      keyOut[pos] = key;
      idOut[pos] = id;
    }
  }
}

// Pass 2 variant: final position -> write rank/inv directly (no key/id output).
__global__ __launch_bounds__(64) void k_rscatter2(const unsigned* __restrict__ keyIn, const unsigned* __restrict__ idIn,
                                                  unsigned* __restrict__ histMat, const unsigned* __restrict__ base,
                                                  int* __restrict__ rank, int* __restrict__ inv) {
  int t = threadIdx.x;
  int tile = blockIdx.x;
  for (int c = 0; c < RTILE / 64; c++) {
    int idx = tile * RTILE + c * 64 + t;
    int valid = idx < NN;
    unsigned key = 0u, id = 0u;
    if (valid) {
      key = keyIn[idx];
      id = idIn[idx];
    }
    unsigned d = key >> 16;
    unsigned long long same = __ballot(valid != 0);
    if (!valid) same = ~same;
#pragma unroll
    for (int b = 0; b < 16; b++) {
      unsigned long long bb = __ballot((int)((d >> b) & 1u));
      same &= ((d >> b) & 1u) ? bb : ~bb;
    }
    unsigned long long lower = (t == 0) ? 0ull : (same << (64 - t) >> (64 - t));
    unsigned intrar = (unsigned)__popcll(lower);
    unsigned total = (unsigned)__popcll(same);
    int leader = (int)(__ffsll((long long)same) - 1);
    unsigned old = 0u;
    if (valid && t == leader) old = atomicAdd(&histMat[(size_t)tile * 65536 + d], total);
    unsigned basec = (unsigned)__shfl((int)old, leader, 64);
    if (valid) {
      unsigned pos = base[d] + basec + intrar;
      rank[(int)id] = (int)pos;
      if (pos < KK) inv[pos] = (int)id;
    }
  }
}

// ---------------- masked aggregation for conv3, branch-free unroll-4 ----------------
__global__ __launch_bounds__(256) void k_agg3(const int* __restrict__ rank, const int* __restrict__ rowp,
                                              const int* __restrict__ csr, unsigned short* __restrict__ A16) {
  long gt = (long)blockIdx.x * 256 + threadIdx.x;
  int n = (int)(gt >> 4), lane = (int)(gt & 15);
  if (n >= NN) return;
  int r = rank[n];
  if (r >= KK) return;
  int beg = rowp[n], end = rowp[n + 1];
  float a0 = 0.f, a1 = 0.f, a2 = 0.f, a3 = 0.f, a4 = 0.f, a5 = 0.f, a6 = 0.f, a7 = 0.f;
  int e = beg;
  for (; e + 4 <= end; e += 4) {
    int s0 = csr[e], s1 = csr[e + 1], s2 = csr[e + 2], s3 = csr[e + 3];
    int r0 = rank[s0], r1 = rank[s1], r2 = rank[s2], r3 = rank[s3];
    r0 = min(r0, KK); r1 = min(r1, KK); r2 = min(r2, KK); r3 = min(r3, KK);
    uint4 v0 = *(const uint4*)&A16[(size_t)r0 * 256 + 128 + lane * 8];
    uint4 v1 = *(const uint4*)&A16[(size_t)r1 * 256 + 128 + lane * 8];
    uint4 v2 = *(const uint4*)&A16[(size_t)r2 * 256 + 128 + lane * 8];
    uint4 v3 = *(const uint4*)&A16[(size_t)r3 * 256 + 128 + lane * 8];
    a0 += bf2f(v0.x & 0xFFFFu) + bf2f(v1.x & 0xFFFFu) + bf2f(v2.x & 0xFFFFu) + bf2f(v3.x & 0xFFFFu);
    a1 += bf2f(v0.x >> 16)     + bf2f(v1.x >> 16)     + bf2f(v2.x >> 16)     + bf2f(v3.x >> 16);
    a2 += bf2f(v0.y & 0xFFFFu) + bf2f(v1.y & 0xFFFFu) + bf2f(v2.y & 0xFFFFu) + bf2f(v3.y & 0xFFFFu);
    a3 += bf2f(v0.y >> 16)     + bf2f(v1.y >> 16)     + bf2f(v2.y >> 16)     + bf2f(v3.y >> 16);
    a4 += bf2f(v0.z & 0xFFFFu) + bf2f(v1.z & 0xFFFFu) + bf2f(v2.z & 0xFFFFu) + bf2f(v3.z & 0xFFFFu);
    a5 += bf2f(v0.z >> 16)     + bf2f(v1.z >> 16)     + bf2f(v2.z >> 16)     + bf2f(v3.z >> 16);
    a6 += bf2f(v0.w & 0xFFFFu) + bf2f(v1.w & 0xFFFFu) + bf2f(v2.w & 0xFFFFu) + bf2f(v3.w & 0xFFFFu);
    a7 += bf2f(v0.w >> 16)     + bf2f(v1.w >> 16)     + bf2f(v2.w >> 16)     + bf2f(v3.w >> 16);
  }
  for (; e < end; e++) {
    int s = csr[e];
    int rs = min(rank[s], KK);
    uint4 v = *(const uint4*)&A16[(size_t)rs * 256 + 128 + lane * 8];
    a0 += bf2f(v.x & 0xFFFFu); a1 += bf2f(v.x >> 16);
    a2 += bf2f(v.y & 0xFFFFu); a3 += bf2f(v.y >> 16);
    a4 += bf2f(v.z & 0xFFFFu); a5 += bf2f(v.z >> 16);
    a6 += bf2f(v.w & 0xFFFFu); a7 += bf2f(v.w >> 16);
  }
  uint4 o;
  o.x = (unsigned)f2bf(a0) | ((unsigned)f2bf(a1) << 16);
  o.y = (unsigned)f2bf(a2) | ((unsigned)f2bf(a3) << 16);
  o.z = (unsigned)f2bf(a4) | ((unsigned)f2bf(a5) << 16);
  o.w = (unsigned)f2bf(a6) | ((unsigned)f2bf(a7) << 16);
  *(uint4*)&A16[(size_t)r * 256 + lane * 8] = o;
}

// ---------------- gated root features -> bf16 A-matrix cols [128,256); row KK zeroed ----------------
__global__ __launch_bounds__(256) void k_gate(const float* __restrict__ h3, const float* __restrict__ scor,
                                              const int* __restrict__ inv, unsigned short* __restrict__ A16) {
  int gt = blockIdx.x * 256 + threadIdx.x;
  int r = gt >> 4, lane = gt & 15;   // 16 threads/row, 8 cols each
  if (r > KK) return;
  if (r == KK) {  // dummy row for branch-free clamp in k_agg3
    *(uint4*)&A16[(size_t)KK * 256 + 128 + lane * 8] = make_uint4(0u, 0u, 0u, 0u);
    return;
  }
  int nd = inv[r];
  float g = scor[nd];
  const float4* src = (const float4*)&h3[(size_t)nd * 128 + lane * 8];
  float4 v0 = src[0], v1 = src[1];
  uint4 o;
  o.x = (unsigned)f2bf(v0.x * g) | ((unsigned)f2bf(v0.y * g) << 16);
  o.y = (unsigned)f2bf(v0.z * g) | ((unsigned)f2bf(v0.w * g) << 16);
  o.z = (unsigned)f2bf(v1.x * g) | ((unsigned)f2bf(v1.y * g) << 16);
  o.w = (unsigned)f2bf(v1.z * g) | ((unsigned)f2bf(v1.w * g) << 16);
  *(uint4*)&A16[(size_t)r * 256 + 128 + lane * 8] = o;
}

// ---------------- W^T bf16 for conv3: W16[col][k] ----------------
__global__ __launch_bounds__(256) void k_wcvt(const float* __restrict__ w3rel, const float* __restrict__ w3root,
                                              unsigned short* __restrict__ W16) {
  int idx = blockIdx.x * 256 + threadIdx.x;  // 65536
  int k = idx >> 8, c = idx & 255;
  float v = (k < 128) ? w3rel[(size_t)k * 256 + c] : w3root[(size_t)(k - 128) * 256 + c];
  W16[(size_t)c * 256 + k] = f2bf(v);
}

// ---------------- conv3 MFMA GEMM + fused parity pooling ----------------
__global__ __launch_bounds__(256) void k_gemm3m(const unsigned short* __restrict__ A16,
                                                const unsigned short* __restrict__ W16,
                                                const float* __restrict__ bias,
                                                float* __restrict__ psum) {
  __shared__ unsigned short Al[64][40];
  __shared__ unsigned short Bl[256][40];
  __shared__ float red[512];
  int t = threadIdx.x;
  int wv = t >> 6, l = t & 63;
  int n0 = blockIdx.x * 64;
  f32x4 acc[4][4];
#pragma unroll
  for (int m = 0; m < 4; m++)
#pragma unroll
    for (int n = 0; n < 4; n++) acc[m][n] = (f32x4){0.f, 0.f, 0.f, 0.f};
  for (int k0 = 0; k0 < 256; k0 += 32) {
    {  // stage A: 64 rows x 32 k
      int row = t >> 2, koff = (t & 3) * 8;
      int gr = n0 + row;
      uint4 v = make_uint4(0u, 0u, 0u, 0u);
      if (gr < KK) v = *(const uint4*)&A16[(size_t)gr * 256 + k0 + koff];
      *(uint4*)&Al[row][koff] = v;
    }
    {  // stage B: 256 cols x 32 k (from pre-transposed W16, fully coalesced)
      int c0 = t >> 2, slot = t & 3;
#pragma unroll
      for (int i = 0; i < 4; i++) {
        int col = c0 + 64 * i;
        uint4 v = *(const uint4*)&W16[(size_t)col * 256 + k0 + slot * 8];
        *(uint4*)&Bl[col][slot * 8] = v;
      }
    }
    __syncthreads();
    int kf = (l >> 4) * 8;
    bf16x8 a[4], b[4];
#pragma unroll
    for (int m = 0; m < 4; m++) a[m] = *(const bf16x8*)&Al[16 * m + (l & 15)][kf];
#pragma unroll
    for (int n = 0; n < 4; n++) b[n] = *(const bf16x8*)&Bl[wv * 64 + 16 * n + (l & 15)][kf];
#pragma unroll
    for (int m = 0; m < 4; m++)
#pragma unroll
      for (int n = 0; n < 4; n++)
        acc[m][n] = __builtin_amdgcn_mfma_f32_16x16x32_bf16(a[m], b[n], acc[m][n], 0, 0, 0);
    __syncthreads();
  }
  for (int i = t; i < 512; i += 256) red[i] = 0.f;
  __syncthreads();
  int rbase = (l >> 4) * 4;
#pragma unroll
  for (int n = 0; n < 4; n++) {
    int col = wv * 64 + 16 * n + (l & 15);
    float bs = bias[col];
#pragma unroll
    for (int j = 0; j < 4; j++) {
      float s = 0.f;
#pragma unroll
      for (int m = 0; m < 4; m++) {
        int row = n0 + 16 * m + rbase + j;
        if (row < KK) s += gelu_f(acc[m][n][j] + bs);
      }
      atomicAdd(&red[(j & 1) * 256 + col], s);
    }
  }
  __syncthreads();
  for (int i = t; i < 512; i += 256) atomicAdd(&psum[i], red[i]);
}

// ---------------- final head ----------------
__global__ __launch_bounds__(512) void k_final(const float* __restrict__ psum, const float* __restrict__ wout,
                                               const float* __restrict__ bout, float* __restrict__ out) {
  __shared__ float red[512];
  int t = threadIdx.x;
  red[t] = psum[t] * (1.0f / 15000.0f) * wout[t];
  __syncthreads();
  for (int s = 256; s > 0; s >>= 1) { if (t < s) red[t] += red[t + s]; __syncthreads(); }
  if (t == 0) out[0] = red[0] + bout[0];
}

extern "C" void kernel_launch(void* const* d_in, const int* in_sizes, int n_in,
                              void* d_out, int out_size, void* d_ws, size_t ws_size,
                              hipStream_t stream) {
  const float* x      = (const float*)d_in[0];
  const int*   ei     = (const int*)d_in[1];
  const float* wdr    = (const float*)d_in[2];
  const float* wdb    = (const float*)d_in[3];
  const float* w0rel  = (const float*)d_in[4];
  const float* w0root = (const float*)d_in[5];
  const float* w0b    = (const float*)d_in[6];
  const float* w1rel  = (const float*)d_in[7];
  const float* w1root = (const float*)d_in[8];
  const float* w1b    = (const float*)d_in[9];
  const float* w2rel  = (const float*)d_in[10];
  const float* w2root = (const float*)d_in[11];
  const float* w2b    = (const float*)d_in[12];
  const float* poolp  = (const float*)d_in[13];
  const float* w3rel  = (const float*)d_in[14];
  const float* w3root = (const float*)d_in[15];
  const float* w3b    = (const float*)d_in[16];
  const float* wout   = (const float*)d_in[17];
  const float* bout   = (const float*)d_in[18];
  float* out = (float*)d_out;

  char* ws = (char*)d_ws;
  size_t o = 0;
  auto alloc = [&](size_t bytes) { size_t r = o; o += (bytes + 255) & ~(size_t)255; return r; };
  // --- zeroed block (one memset) ---
  size_t o_psum = alloc(512 * 4);
  size_t zbytes = o;
  // --- fully-written buffers ---
  size_t o_rowp = alloc((size_t)(NN + 1) * 4);
  size_t o_csr  = alloc((size_t)EE * 4);
  size_t o_h0   = alloc((size_t)NN * 4 * 4);
  size_t o_h1   = alloc((size_t)NN * 32 * 4);   // NOTE: h1+h2 region re-used as A16 after radix
  size_t o_h2   = alloc((size_t)NN * 64 * 4);   // also aliased as radix histMat after conv2
  size_t o_h3   = alloc((size_t)NN * 128 * 4);
  size_t o_agg  = alloc((size_t)NN * 64 * 4);   // also aliased as chunkEdges during CSR build
  size_t o_scor = alloc((size_t)NN * 4);
  size_t o_skey = alloc((size_t)NN * 4);
  size_t o_rank = alloc((size_t)NN * 4);
  size_t o_inv  = alloc((size_t)KK * 4);
  size_t o_keyB = alloc((size_t)NN * 4);
  size_t o_idB  = alloc((size_t)NN * 4);
  size_t o_tot  = alloc(65536 * 4);
  size_t o_bsB  = alloc(1024 * 4);
  size_t o_W16  = alloc((size_t)256 * 256 * 2);
  size_t o_W1T  = alloc((size_t)64 * 64 * 2);
  size_t o_W2T  = alloc((size_t)128 * 128 * 2);
  size_t o_cbase = alloc((size_t)GBLK * (BKT + 1) * 4);
  size_t o_bbase = alloc((size_t)(BKT + 1) * 4);
  (void)ws_size; (void)in_sizes; (void)n_in; (void)out_size;

  float*    psum = (float*)(ws + o_psum);
  int*      rowp = (int*)(ws + o_rowp);
  int*      csr  = (int*)(ws + o_csr);
  float*    h0   = (float*)(ws + o_h0);
  float*    h1   = (float*)(ws + o_h1);
  float*    h2   = (float*)(ws + o_h2);
  float*    h3   = (float*)(ws + o_h3);
  float*    agg  = (float*)(ws + o_agg);
  float*    scor = (float*)(ws + o_scor);
  unsigned* skey = (unsigned*)(ws + o_skey);
  int*      rank = (int*)(ws + o_rank);
  int*      inv  = (int*)(ws + o_inv);
  unsigned* keyB = (unsigned*)(ws + o_keyB);
  unsigned* idB  = (unsigned*)(ws + o_idB);
  unsigned* tot  = (unsigned*)(ws + o_tot);
  unsigned* bsB  = (unsigned*)(ws + o_bsB);
  unsigned* hist = (unsigned*)(ws + o_h2);            // alias: h2 dead after conv2 GEMM
  unsigned short* A16 = (unsigned short*)(ws + o_h1); // alias: h1+h2 dead after radix; (KK+1) rows fit
  unsigned short* W16 = (unsigned short*)(ws + o_W16);
  unsigned short* W1T = (unsigned short*)(ws + o_W1T);
  unsigned short* W2T = (unsigned short*)(ws + o_W2T);
  unsigned* chunkEdges = (unsigned*)(ws + o_agg);     // alias: agg unused until conv0
  int*      chunkBase  = (int*)(ws + o_cbase);
  unsigned* bktBase    = (unsigned*)(ws + o_bbase);

  hipMemsetAsync(ws, 0, zbytes, stream);

  const int* src = ei;
  const int* dstp = ei + EE;

  // CSR build (reused by all 4 convs): chunk bucket-sort -> bucket scan -> per-bucket rowp+csr
  k_binA<<<GBLK, 512, 0, stream>>>(src, dstp, chunkEdges, chunkBase);
  k_bktsum<<<1, 512, 0, stream>>>(chunkBase, bktBase);
  k_binC<<<BKT, 256, 0, stream>>>(chunkEdges, chunkBase, bktBase, rowp, csr);

  // weight pre-convert (tiny; any time before the gemms)
  k_wcvtT<32, 64><<<(64 * 64) / 256, 256, 0, stream>>>(w1rel, w1root, W1T);
  k_wcvtT<64, 128><<<(128 * 128) / 256, 256, 0, stream>>>(w2rel, w2root, W2T);
  k_wcvt<<<256, 256, 0, stream>>>(w3rel, w3root, W16);

  // dense input layer
  k_dense<<<(NN + 255) / 256, 256, 0, stream>>>(x, wdr, wdb, h0);

  // conv0: 4 -> 32
  k_agg<1><<<(NN + 255) / 256, 256, 0, stream>>>(h0, rowp, csr, agg);
  k_gemm0<<<(NN * 32 + 255) / 256, 256, 0, stream>>>(agg, h0, w0rel, w0root, w0b, h1);

  // conv1: 32 -> 64 (bf16 MFMA)
  k_agg<8><<<(NN * 8 + 255) / 256, 256, 0, stream>>>(h1, rowp, csr, agg);
  k_gemmM<32, 64><<<(NN + 63) / 64, 256, 0, stream>>>(agg, h1, W1T, w1b, h2, NN);

  // conv2: 64 -> 128 (bf16 MFMA)
  k_agg<16><<<(NN * 16 + 255) / 256, 256, 0, stream>>>(h2, rowp, csr, agg);
  k_gemmM<64, 128><<<(NN + 63) / 64, 256, 0, stream>>>(agg, h2, W2T, w2b, h3, NN);

  // score + key + fused radix pass-1 histogram (hist aliases h2: dead after conv2 GEMM)
  hipMemsetAsync(hist, 0, (size_t)NTILES * 65536 * 4, stream);
  k_score<<<(NN + 7) / 8, 256, 0, stream>>>(h3, poolp, scor, skey, hist);

  // ---- radix sort pass 1 (low 16 bits) ----
  k_rtileprefix<<<65536 / 256, 256, 0, stream>>>(hist, tot);
  k_scanA<<<64, 1024, 0, stream>>>(tot, tot, bsB, 65536);
  k_scanB<<<1, 1024, 0, stream>>>(bsB, 64);
  k_scanC<<<64, 1024, 0, stream>>>(tot, bsB, 65536);
  k_rscatter<0, true><<<NTILES, 64, 0, stream>>>(skey, nullptr, hist, tot, keyB, idB);

  // ---- radix sort pass 2 (high 16 bits), fused rank/inv write ----
  hipMemsetAsync(hist, 0, (size_t)NTILES * 65536 * 4, stream);
  k_rhist<16><<<(NN + 255) / 256, 256, 0, stream>>>(keyB, hist);
  k_rtileprefix<<<65536 / 256, 256, 0, stream>>>(hist, tot);
  k_scanA<<<64, 1024, 0, stream>>>(tot, tot, bsB, 65536);
  k_scanB<<<1, 1024, 0, stream>>>(bsB, 64);
  k_scanC<<<64, 1024, 0, stream>>>(tot, bsB, 65536);
  k_rscatter2<<<NTILES, 64, 0, stream>>>(keyB, idB, hist, tot, rank, inv);

  // conv3: 128 -> 256 on kept nodes via bf16 MFMA, fused parity pooling
  k_gate<<<((KK + 1) * 16 + 255) / 256, 256, 0, stream>>>(h3, scor, inv, A16);
  k_agg3<<<((long)NN * 16 + 255) / 256, 256, 0, stream>>>(rank, rowp, csr, A16);
  k_gemm3m<<<(KK + 63) / 64, 256, 0, stream>>>(A16, W16, w3b, psum);

  // head
  k_final<<<1, 512, 0, stream>>>(psum, wout, bout, out);
}

// Round 13
// 502.352 us; speedup vs baseline: 1.0252x; 1.0252x over previous
//
#include <hip/hip_runtime.h>
#include <hip/hip_bf16.h>
#include <math.h>

#define NN 50000
#define EE 1600000
#define KK 30000
#define RTILE 1088   // 17 * 64
#define NTILES 48    // 48*1088 = 52224 >= NN
#define CHUNK 16384
#define GBLK 98      // ceil(EE/CHUNK)
#define BKT 391      // ceil(NN/128)
#define CMAX 6144    // bucket CSR staging cap (avg 4092, sigma 64)

typedef __attribute__((ext_vector_type(8))) short bf16x8;  // 8 bf16 = 4 VGPR (MFMA A/B frag)
typedef __attribute__((ext_vector_type(4))) float f32x4;   // MFMA C/D frag

__device__ __forceinline__ float gelu_f(float v) {
  return 0.5f * v * (1.0f + erff(v * 0.70710678118654752440f));
}

__device__ __forceinline__ unsigned short f2bf(float x) {
  __hip_bfloat16 h = __float2bfloat16(x);   // RNE
  return *(unsigned short*)&h;
}

__device__ __forceinline__ float bf2f(unsigned u16) {  // low 16 bits hold bf16
  return __uint_as_float(u16 << 16);
}

__device__ __forceinline__ bf16x8 pack8(float4 v0, float4 v1) {
  union { unsigned u[4]; bf16x8 b; } r;
  r.u[0] = (unsigned)f2bf(v0.x) | ((unsigned)f2bf(v0.y) << 16);
  r.u[1] = (unsigned)f2bf(v0.z) | ((unsigned)f2bf(v0.w) << 16);
  r.u[2] = (unsigned)f2bf(v1.x) | ((unsigned)f2bf(v1.y) << 16);
  r.u[3] = (unsigned)f2bf(v1.z) | ((unsigned)f2bf(v1.w) << 16);
  return r.b;
}

// ---------------- generic multi-block exclusive scan (used by radix digit scan) ----------------
__global__ __launch_bounds__(1024) void k_scanA(const unsigned* __restrict__ in, unsigned* __restrict__ out,
                                                unsigned* __restrict__ bsum, int n) {
  __shared__ unsigned sh[1024];
  int t = threadIdx.x;
  int i = blockIdx.x * 1024 + t;
  unsigned v = (i < n) ? in[i] : 0u;
  sh[t] = v;
  __syncthreads();
  for (int ofs = 1; ofs < 1024; ofs <<= 1) {
    unsigned add = (t >= ofs) ? sh[t - ofs] : 0u;
    __syncthreads();
    sh[t] += add;
    __syncthreads();
  }
  if (i < n) out[i] = sh[t] - v;  // exclusive
  if (t == 1023) bsum[blockIdx.x] = sh[1023];
}

__global__ __launch_bounds__(1024) void k_scanB(unsigned* __restrict__ bsum, int nb) {
  __shared__ unsigned sh[1024];
  int t = threadIdx.x;
  unsigned v = (t < nb) ? bsum[t] : 0u;
  sh[t] = v;
  __syncthreads();
  for (int ofs = 1; ofs < 1024; ofs <<= 1) {
    unsigned add = (t >= ofs) ? sh[t - ofs] : 0u;
    __syncthreads();
    sh[t] += add;
    __syncthreads();
  }
  if (t < nb) bsum[t] = sh[t] - v;  // exclusive block offsets
}

__global__ __launch_bounds__(1024) void k_scanC(unsigned* __restrict__ out, const unsigned* __restrict__ bsum, int n) {
  int i = blockIdx.x * 1024 + threadIdx.x;
  if (i < n) out[i] += bsum[blockIdx.x];  // bsum[0]==0
}

// ---------------- binned CSR fill, phase A: chunk-local bucket sort (all-coalesced global I/O) ----------------
__global__ __launch_bounds__(512) void k_binA(const int* __restrict__ src, const int* __restrict__ dst,
                                              unsigned* __restrict__ chunkEdges, int* __restrict__ chunkBase) {
  __shared__ int hist[BKT];
  __shared__ int scanb[512];
  __shared__ unsigned buf[CHUNK];
  int t = threadIdx.x, g = blockIdx.x;
  int e0 = g * CHUNK;
  int n = EE - e0; if (n > CHUNK) n = CHUNK;
  for (int i = t; i < BKT; i += 512) hist[i] = 0;
  __syncthreads();
  for (int i = t; i < n; i += 512) atomicAdd(&hist[dst[e0 + i] >> 7], 1);
  __syncthreads();
  int v = (t < BKT) ? hist[t] : 0;
  scanb[t] = v;
  __syncthreads();
  for (int ofs = 1; ofs < 512; ofs <<= 1) {
    int a = (t >= ofs) ? scanb[t - ofs] : 0;
    __syncthreads();
    scanb[t] += a;
    __syncthreads();
  }
  if (t < BKT) {
    scanb[t] -= v;
    chunkBase[g * (BKT + 1) + t] = scanb[t];
    hist[t] = 0;  // reuse as running counters
  }
  if (t == 0) chunkBase[g * (BKT + 1) + BKT] = n;
  __syncthreads();
  for (int i = t; i < n; i += 512) {
    int d = dst[e0 + i], s = src[e0 + i];
    int b = d >> 7;
    int pos = scanb[b] + atomicAdd(&hist[b], 1);
    buf[pos] = ((unsigned)(d & 127) << 16) | (unsigned)s;
  }
  __syncthreads();
  for (int i = t; i < n; i += 512) chunkEdges[e0 + i] = buf[i];
}

// ---------------- bucket totals + exclusive scan -> bktBase ----------------
__global__ __launch_bounds__(512) void k_bktsum(const int* __restrict__ chunkBase, unsigned* __restrict__ bktBase) {
  __shared__ unsigned sh[512];
  int t = threadIdx.x;
  unsigned s = 0;
  if (t < BKT) {
    for (int g = 0; g < GBLK; g++)
      s += (unsigned)(chunkBase[g * (BKT + 1) + t + 1] - chunkBase[g * (BKT + 1) + t]);
  }
  sh[t] = s;
  __syncthreads();
  for (int ofs = 1; ofs < 512; ofs <<= 1) {
    unsigned a = (t >= ofs) ? sh[t - ofs] : 0u;
    __syncthreads();
    sh[t] += a;
    __syncthreads();
  }
  if (t < BKT) bktBase[t] = sh[t] - s;  // exclusive
  if (t == 0) bktBase[BKT] = EE;
}

// ---------------- binned CSR fill, phase C: gather + LDS count/scan -> rowp + csr ----------------
__global__ __launch_bounds__(256) void k_binC(const unsigned* __restrict__ chunkEdges, const int* __restrict__ chunkBase,
                                              const unsigned* __restrict__ bktBase,
                                              int* __restrict__ rowp, int* __restrict__ csr) {
  __shared__ int segS[GBLK + 1];
  __shared__ int cnt[128];
  __shared__ int loc[128];
  __shared__ unsigned eBuf[CMAX];
  __shared__ int csrB[CMAX];
  int t = threadIdx.x, b = blockIdx.x;
  int n0 = b << 7;
  int nb = NN - n0; if (nb > 128) nb = 128;
  if (t < GBLK) segS[t] = chunkBase[t * (BKT + 1) + b + 1] - chunkBase[t * (BKT + 1) + b];
  if (t < 128) cnt[t] = 0;
  __syncthreads();
  if (t == 0) {
    int run = 0;
    for (int g = 0; g < GBLK; g++) { int L = segS[g]; segS[g] = run; run += L; }
    segS[GBLK] = run;
  }
  __syncthreads();
  int total = segS[GBLK];
  for (int i = t; i < total; i += 256) {
    int lo = 0, hi = GBLK - 1;
    while (lo < hi) { int mid = (lo + hi + 1) >> 1; if (segS[mid] <= i) lo = mid; else hi = mid - 1; }
    int off = chunkBase[lo * (BKT + 1) + b] + (i - segS[lo]);
    unsigned v = chunkEdges[lo * CHUNK + off];
    if (i < CMAX) eBuf[i] = v;
    atomicAdd(&cnt[v >> 16], 1);
  }
  __syncthreads();
  if (t < 128) loc[t] = cnt[t];
  __syncthreads();
  for (int ofs = 1; ofs < 128; ofs <<= 1) {
    int a = (t < 128 && t >= ofs) ? loc[t - ofs] : 0;
    __syncthreads();
    if (t < 128) loc[t] += a;
    __syncthreads();
  }
  if (t < 128) loc[t] -= cnt[t];  // exclusive local offsets
  __syncthreads();
  int base = (int)bktBase[b];
  if (t < nb) rowp[n0 + t] = base + loc[t];
  if (b == BKT - 1 && t == 0) rowp[NN] = base + total;  // == EE
  if (t < 128) cnt[t] = 0;  // reuse as running counters
  __syncthreads();
  for (int i = t; i < total && i < CMAX; i += 256) {
    unsigned v = eBuf[i];
    int d = (int)(v >> 16);
    int pos = loc[d] + atomicAdd(&cnt[d], 1);
    if (pos < CMAX) csrB[pos] = (int)(v & 0xFFFFu);
  }
  __syncthreads();
  for (int i = t; i < total && i < CMAX; i += 256) csr[base + i] = csrB[i];
}

// ---------------- dense input layer: h0 = gelu(x @ wd_root + b) ----------------
__global__ __launch_bounds__(256) void k_dense(const float* __restrict__ x, const float* __restrict__ w,
                                               const float* __restrict__ b, float* __restrict__ h0) {
  __shared__ float ws[260];
  int t = threadIdx.x;
  ws[t] = w[t];                    // w is 64*4 = 256
  if (t < 4) ws[256 + t] = b[t];
  __syncthreads();
  int n = blockIdx.x * 256 + t;
  if (n >= NN) return;
  float acc0 = ws[256], acc1 = ws[257], acc2 = ws[258], acc3 = ws[259];
  const float4* xr = (const float4*)(x + (size_t)n * 64);
#pragma unroll
  for (int k4 = 0; k4 < 16; k4++) {
    float4 v = xr[k4];
    const float* wk = &ws[k4 * 16];
    acc0 += v.x * wk[0];  acc1 += v.x * wk[1];  acc2 += v.x * wk[2];  acc3 += v.x * wk[3];
    acc0 += v.y * wk[4];  acc1 += v.y * wk[5];  acc2 += v.y * wk[6];  acc3 += v.y * wk[7];
    acc0 += v.z * wk[8];  acc1 += v.z * wk[9];  acc2 += v.z * wk[10]; acc3 += v.z * wk[11];
    acc0 += v.w * wk[12]; acc1 += v.w * wk[13]; acc2 += v.w * wk[14]; acc3 += v.w * wk[15];
  }
  float4 o;
  o.x = gelu_f(acc0); o.y = gelu_f(acc1); o.z = gelu_f(acc2); o.w = gelu_f(acc3);
  ((float4*)h0)[n] = o;
}

// ---------------- pull aggregation, unroll-4: agg[n][:] = sum_{s in in(n)} h[s][:] ----------------
template <int TPN>
__global__ __launch_bounds__(256) void k_agg(const float* __restrict__ h, const int* __restrict__ rowp,
                                             const int* __restrict__ csr, float* __restrict__ agg) {
  long gt = (long)blockIdx.x * 256 + threadIdx.x;
  int n = (int)(gt / TPN), lane = (int)(gt % TPN);
  if (n >= NN) return;
  int beg = rowp[n], end = rowp[n + 1];
  const float4* hv = (const float4*)h;
  float4 a0 = make_float4(0.f, 0.f, 0.f, 0.f), a1 = a0, a2 = a0, a3 = a0;
  int e = beg;
  for (; e + 4 <= end; e += 4) {
    int s0 = csr[e], s1 = csr[e + 1], s2 = csr[e + 2], s3 = csr[e + 3];
    float4 v0 = hv[(size_t)s0 * TPN + lane];
    float4 v1 = hv[(size_t)s1 * TPN + lane];
    float4 v2 = hv[(size_t)s2 * TPN + lane];
    float4 v3 = hv[(size_t)s3 * TPN + lane];
    a0.x += v0.x; a0.y += v0.y; a0.z += v0.z; a0.w += v0.w;
    a1.x += v1.x; a1.y += v1.y; a1.z += v1.z; a1.w += v1.w;
    a2.x += v2.x; a2.y += v2.y; a2.z += v2.z; a2.w += v2.w;
    a3.x += v3.x; a3.y += v3.y; a3.z += v3.z; a3.w += v3.w;
  }
  for (; e < end; e++) {
    int s = csr[e];
    float4 v = hv[(size_t)s * TPN + lane];
    a0.x += v.x; a0.y += v.y; a0.z += v.z; a0.w += v.w;
  }
  float4 acc;
  acc.x = (a0.x + a1.x) + (a2.x + a3.x);
  acc.y = (a0.y + a1.y) + (a2.y + a3.y);
  acc.z = (a0.z + a1.z) + (a2.z + a3.z);
  acc.w = (a0.w + a1.w) + (a2.w + a3.w);
  ((float4*)agg)[(size_t)n * TPN + lane] = acc;
}

// ---------------- conv0 GEMM (DIN=4 -> DOUT=32) ----------------
__global__ __launch_bounds__(256) void k_gemm0(const float* __restrict__ agg0, const float* __restrict__ h0,
                                               const float* __restrict__ wrel, const float* __restrict__ wroot,
                                               const float* __restrict__ bias, float* __restrict__ h1) {
  __shared__ float ws[288];
  int t = threadIdx.x;
  if (t < 128) { ws[t] = wrel[t]; ws[128 + t] = wroot[t]; }
  if (t < 32) ws[256 + t] = bias[t];
  __syncthreads();
  int gt = blockIdx.x * 256 + t;
  int n = gt >> 5, j = gt & 31;
  if (n >= NN) return;
  float4 a = ((const float4*)agg0)[n];
  float4 h = ((const float4*)h0)[n];
  float acc = ws[256 + j];
  acc += a.x * ws[j]        + a.y * ws[32 + j]  + a.z * ws[64 + j]  + a.w * ws[96 + j];
  acc += h.x * ws[128 + j]  + h.y * ws[160 + j] + h.z * ws[192 + j] + h.w * ws[224 + j];
  h1[(size_t)n * 32 + j] = gelu_f(acc);
}

// ---------------- weight pre-transpose+convert: W16T[col][k] bf16, k in [0,2*DIN) ----------------
template <int DIN, int DOUT>
__global__ __launch_bounds__(256) void k_wcvtT(const float* __restrict__ wrel, const float* __restrict__ wroot,
                                               unsigned short* __restrict__ W16T) {
  constexpr int K = 2 * DIN;
  int idx = blockIdx.x * 256 + threadIdx.x;  // DOUT*K total
  int col = idx / K, k = idx % K;
  float v = (k < DIN) ? wrel[(size_t)k * DOUT + col] : wroot[(size_t)(k - DIN) * DOUT + col];
  W16T[(size_t)col * K + k] = f2bf(v);
}

// ---------------- LDS-free MFMA conv GEMM: Cout = gelu(bf16([agg|h]) @ W + b), fp32 accum ----------------
// Block 256 = 4 waves; tile 64 rows x DOUT cols; wave wv owns cols [wv*DOUT/4, ...+DOUT/4).
// A and B fragments loaded DIRECTLY from global (L2/L3-resident): no LDS, no barriers.
// A-frag layout (verified m89/m91): row = l&15 (+16m), k = (l>>4)*8 + j.
// Rows >= R are clamped to R-1; their garbage stays in their own C rows, which the epilogue skips.
template <int DIN, int DOUT>
__global__ __launch_bounds__(256) void k_gemmM(const float* __restrict__ Ag, const float* __restrict__ Hp,
                                               const unsigned short* __restrict__ W16T,
                                               const float* __restrict__ bias, float* __restrict__ Cout, int R) {
  constexpr int K = 2 * DIN;
  constexpr int NF = DOUT / 64;   // 16-col frags per wave
  int t = threadIdx.x;
  int wv = t >> 6, l = t & 63;
  int n0 = blockIdx.x * 64;
  int lane16 = l & 15, kf = (l >> 4) * 8;
  f32x4 acc[4][NF];
#pragma unroll
  for (int m = 0; m < 4; m++)
#pragma unroll
    for (int n = 0; n < NF; n++) acc[m][n] = (f32x4){0.f, 0.f, 0.f, 0.f};
  int rowm[4];
#pragma unroll
  for (int m = 0; m < 4; m++) rowm[m] = min(n0 + 16 * m + lane16, R - 1);
#pragma unroll
  for (int kc = 0; kc < K; kc += 32) {
    const float* srcp = (kc < DIN) ? Ag : Hp;
    int kbase = ((kc < DIN) ? kc : (kc - DIN)) + kf;
    bf16x8 a[4], b[NF];
#pragma unroll
    for (int m = 0; m < 4; m++) {
      const float* rp = srcp + (size_t)rowm[m] * DIN + kbase;
      float4 v0 = *(const float4*)rp;
      float4 v1 = *(const float4*)(rp + 4);
      a[m] = pack8(v0, v1);
    }
#pragma unroll
    for (int n = 0; n < NF; n++)
      b[n] = *(const bf16x8*)&W16T[(size_t)(wv * (DOUT / 4) + 16 * n + lane16) * K + kc + kf];
#pragma unroll
    for (int m = 0; m < 4; m++)
#pragma unroll
      for (int n = 0; n < NF; n++)
        acc[m][n] = __builtin_amdgcn_mfma_f32_16x16x32_bf16(a[m], b[n], acc[m][n], 0, 0, 0);
  }
  // epilogue: row = n0 + 16m + (l>>4)*4 + j; col = wv*(DOUT/4) + 16n + (l&15)
  int rb = (l >> 4) * 4;
#pragma unroll
  for (int n = 0; n < NF; n++) {
    int col = wv * (DOUT / 4) + 16 * n + lane16;
    float bs = bias[col];
#pragma unroll
    for (int m = 0; m < 4; m++) {
#pragma unroll
      for (int j = 0; j < 4; j++) {
        int r = n0 + 16 * m + rb + j;
        if (r < R) Cout[(size_t)r * DOUT + col] = gelu_f(acc[m][n][j] + bs);
      }
    }
  }
}

// ---------------- score = tanh(h3 . p / ||p||); key + fused pass-1 histogram ----------------
__global__ __launch_bounds__(256) void k_score(const float* __restrict__ h3, const float* __restrict__ p,
                                               float* __restrict__ score, unsigned* __restrict__ skey,
                                               unsigned* __restrict__ hist) {
  __shared__ float red[256];
  int t = threadIdx.x;
  float pv = 0.f;
  if (t < 128) { float q = p[t]; pv = q * q; }
  red[t] = pv;
  __syncthreads();
  for (int s = 128; s > 0; s >>= 1) { if (t < s) red[t] += red[t + s]; __syncthreads(); }
  float pinv = rsqrtf(red[0]);
  int n = blockIdx.x * 8 + (t >> 5);
  int lane = t & 31;
  if (n >= NN) return;
  float4 hv = ((const float4*)(h3 + (size_t)n * 128))[lane];
  float4 pw = ((const float4*)p)[lane];
  float d = hv.x * pw.x + hv.y * pw.y + hv.z * pw.z + hv.w * pw.w;
  for (int o = 16; o > 0; o >>= 1) d += __shfl_xor(d, o, 32);
  if (lane == 0) {
    float sc = tanhf(d * pinv);
    score[n] = sc;
    unsigned bits = __float_as_uint(sc);
    unsigned mono = (bits & 0x80000000u) ? ~bits : (bits | 0x80000000u);
    unsigned sk = ~mono;  // ascending key == descending score; stable sort -> ties by index
    skey[n] = sk;
    atomicAdd(&hist[(size_t)(n / RTILE) * 65536 + (sk & 0xFFFFu)], 1u);  // radix pass-1 hist
  }
}

// ---------------- radix sort (2 x 16-bit passes, stable) ----------------
template <int SHIFT>
__global__ __launch_bounds__(256) void k_rhist(const unsigned* __restrict__ keyIn, unsigned* __restrict__ histMat) {
  int gid = blockIdx.x * 256 + threadIdx.x;
  if (gid < NN) {
    unsigned d = (keyIn[gid] >> SHIFT) & 0xFFFFu;
    int tile = gid / RTILE;
    atomicAdd(&histMat[(size_t)tile * 65536 + d], 1u);
  }
}

__global__ __launch_bounds__(256) void k_rtileprefix(unsigned* __restrict__ histMat, unsigned* __restrict__ total) {
  int d = blockIdx.x * 256 + threadIdx.x;  // 65536 threads
  unsigned run = 0;
  for (int tl = 0; tl < NTILES; tl++) {
    size_t ix = (size_t)tl * 65536 + d;
    unsigned v = histMat[ix];
    histMat[ix] = run;
    run += v;
  }
  total[d] = run;
}

// One wave per block; ballot-based stable scatter, no LDS. Pass 1: writes key+id.
template <int SHIFT, bool FIRST>
__global__ __launch_bounds__(64) void k_rscatter(const unsigned* __restrict__ keyIn, const unsigned* __restrict__ idIn,
                                                 unsigned* __restrict__ histMat, const unsigned* __restrict__ base,
                                                 unsigned* __restrict__ keyOut, unsigned* __restrict__ idOut) {
  int t = threadIdx.x;
  int tile = blockIdx.x;
  for (int c = 0; c < RTILE / 64; c++) {
    int idx = tile * RTILE + c * 64 + t;
    int valid = idx < NN;
    unsigned key = 0u, id = 0u;
    if (valid) {
      key = keyIn[idx];
      id = FIRST ? (unsigned)idx : idIn[idx];
    }
    unsigned d = (key >> SHIFT) & 0xFFFFu;
    unsigned long long same = __ballot(valid != 0);
    if (!valid) same = ~same;
#pragma unroll
    for (int b = 0; b < 16; b++) {
      unsigned long long bb = __ballot((int)((d >> b) & 1u));
      same &= ((d >> b) & 1u) ? bb : ~bb;
    }
    unsigned long long lower = (t == 0) ? 0ull : (same << (64 - t) >> (64 - t));  // bits [0,t)
    unsigned intrar = (unsigned)__popcll(lower);
    unsigned total = (unsigned)__popcll(same);
    int leader = (int)(__ffsll((long long)same) - 1);
    unsigned old = 0u;
    if (valid && t == leader) old = atomicAdd(&histMat[(size_t)tile * 65536 + d], total);
    unsigned basec = (unsigned)__shfl((int)old, leader, 64);
    if (valid) {
      unsigned pos = base[d] + basec + intrar;
      keyOut[pos] = key;
      idOut[pos] = id;
    }
  }
}

// Pass 2 variant: final position -> write rank/inv directly (no key/id output).
__global__ __launch_bounds__(64) void k_rscatter2(const unsigned* __restrict__ keyIn, const unsigned* __restrict__ idIn,
                                                  unsigned* __restrict__ histMat, const unsigned* __restrict__ base,
                                                  int* __restrict__ rank, int* __restrict__ inv) {
  int t = threadIdx.x;
  int tile = blockIdx.x;
  for (int c = 0; c < RTILE / 64; c++) {
    int idx = tile * RTILE + c * 64 + t;
    int valid = idx < NN;
    unsigned key = 0u, id = 0u;
    if (valid) {
      key = keyIn[idx];
      id = idIn[idx];
    }
    unsigned d = key >> 16;
    unsigned long long same = __ballot(valid != 0);
    if (!valid) same = ~same;
#pragma unroll
    for (int b = 0; b < 16; b++) {
      unsigned long long bb = __ballot((int)((d >> b) & 1u));
      same &= ((d >> b) & 1u) ? bb : ~bb;
    }
    unsigned long long lower = (t == 0) ? 0ull : (same << (64 - t) >> (64 - t));
    unsigned intrar = (unsigned)__popcll(lower);
    unsigned total = (unsigned)__popcll(same);
    int leader = (int)(__ffsll((long long)same) - 1);
    unsigned old = 0u;
    if (valid && t == leader) old = atomicAdd(&histMat[(size_t)tile * 65536 + d], total);
    unsigned basec = (unsigned)__shfl((int)old, leader, 64);
    if (valid) {
      unsigned pos = base[d] + basec + intrar;
      rank[(int)id] = (int)pos;
      if (pos < KK) inv[pos] = (int)id;
    }
  }
}

// ---------------- masked aggregation for conv3, branch-free unroll-4 ----------------
__global__ __launch_bounds__(256) void k_agg3(const int* __restrict__ rank, const int* __restrict__ rowp,
                                              const int* __restrict__ csr, unsigned short* __restrict__ A16) {
  long gt = (long)blockIdx.x * 256 + threadIdx.x;
  int n = (int)(gt >> 4), lane = (int)(gt & 15);
  if (n >= NN) return;
  int r = rank[n];
  if (r >= KK) return;
  int beg = rowp[n], end = rowp[n + 1];
  float a0 = 0.f, a1 = 0.f, a2 = 0.f, a3 = 0.f, a4 = 0.f, a5 = 0.f, a6 = 0.f, a7 = 0.f;
  int e = beg;
  for (; e + 4 <= end; e += 4) {
    int s0 = csr[e], s1 = csr[e + 1], s2 = csr[e + 2], s3 = csr[e + 3];
    int r0 = rank[s0], r1 = rank[s1], r2 = rank[s2], r3 = rank[s3];
    r0 = min(r0, KK); r1 = min(r1, KK); r2 = min(r2, KK); r3 = min(r3, KK);
    uint4 v0 = *(const uint4*)&A16[(size_t)r0 * 256 + 128 + lane * 8];
    uint4 v1 = *(const uint4*)&A16[(size_t)r1 * 256 + 128 + lane * 8];
    uint4 v2 = *(const uint4*)&A16[(size_t)r2 * 256 + 128 + lane * 8];
    uint4 v3 = *(const uint4*)&A16[(size_t)r3 * 256 + 128 + lane * 8];
    a0 += bf2f(v0.x & 0xFFFFu) + bf2f(v1.x & 0xFFFFu) + bf2f(v2.x & 0xFFFFu) + bf2f(v3.x & 0xFFFFu);
    a1 += bf2f(v0.x >> 16)     + bf2f(v1.x >> 16)     + bf2f(v2.x >> 16)     + bf2f(v3.x >> 16);
    a2 += bf2f(v0.y & 0xFFFFu) + bf2f(v1.y & 0xFFFFu) + bf2f(v2.y & 0xFFFFu) + bf2f(v3.y & 0xFFFFu);
    a3 += bf2f(v0.y >> 16)     + bf2f(v1.y >> 16)     + bf2f(v2.y >> 16)     + bf2f(v3.y >> 16);
    a4 += bf2f(v0.z & 0xFFFFu) + bf2f(v1.z & 0xFFFFu) + bf2f(v2.z & 0xFFFFu) + bf2f(v3.z & 0xFFFFu);
    a5 += bf2f(v0.z >> 16)     + bf2f(v1.z >> 16)     + bf2f(v2.z >> 16)     + bf2f(v3.z >> 16);
    a6 += bf2f(v0.w & 0xFFFFu) + bf2f(v1.w & 0xFFFFu) + bf2f(v2.w & 0xFFFFu) + bf2f(v3.w & 0xFFFFu);
    a7 += bf2f(v0.w >> 16)     + bf2f(v1.w >> 16)     + bf2f(v2.w >> 16)     + bf2f(v3.w >> 16);
  }
  for (; e < end; e++) {
    int s = csr[e];
    int rs = min(rank[s], KK);
    uint4 v = *(const uint4*)&A16[(size_t)rs * 256 + 128 + lane * 8];
    a0 += bf2f(v.x & 0xFFFFu); a1 += bf2f(v.x >> 16);
    a2 += bf2f(v.y & 0xFFFFu); a3 += bf2f(v.y >> 16);
    a4 += bf2f(v.z & 0xFFFFu); a5 += bf2f(v.z >> 16);
    a6 += bf2f(v.w & 0xFFFFu); a7 += bf2f(v.w >> 16);
  }
  uint4 o;
  o.x = (unsigned)f2bf(a0) | ((unsigned)f2bf(a1) << 16);
  o.y = (unsigned)f2bf(a2) | ((unsigned)f2bf(a3) << 16);
  o.z = (unsigned)f2bf(a4) | ((unsigned)f2bf(a5) << 16);
  o.w = (unsigned)f2bf(a6) | ((unsigned)f2bf(a7) << 16);
  *(uint4*)&A16[(size_t)r * 256 + lane * 8] = o;
}

// ---------------- gated root features -> bf16 A-matrix cols [128,256); row KK zeroed ----------------
__global__ __launch_bounds__(256) void k_gate(const float* __restrict__ h3, const float* __restrict__ scor,
                                              const int* __restrict__ inv, unsigned short* __restrict__ A16) {
  int gt = blockIdx.x * 256 + threadIdx.x;
  int r = gt >> 4, lane = gt & 15;   // 16 threads/row, 8 cols each
  if (r > KK) return;
  if (r == KK) {  // dummy row for branch-free clamp in k_agg3
    *(uint4*)&A16[(size_t)KK * 256 + 128 + lane * 8] = make_uint4(0u, 0u, 0u, 0u);
    return;
  }
  int nd = inv[r];
  float g = scor[nd];
  const float4* src = (const float4*)&h3[(size_t)nd * 128 + lane * 8];
  float4 v0 = src[0], v1 = src[1];
  uint4 o;
  o.x = (unsigned)f2bf(v0.x * g) | ((unsigned)f2bf(v0.y * g) << 16);
  o.y = (unsigned)f2bf(v0.z * g) | ((unsigned)f2bf(v0.w * g) << 16);
  o.z = (unsigned)f2bf(v1.x * g) | ((unsigned)f2bf(v1.y * g) << 16);
  o.w = (unsigned)f2bf(v1.z * g) | ((unsigned)f2bf(v1.w * g) << 16);
  *(uint4*)&A16[(size_t)r * 256 + 128 + lane * 8] = o;
}

// ---------------- W^T bf16 for conv3: W16[col][k] ----------------
__global__ __launch_bounds__(256) void k_wcvt(const float* __restrict__ w3rel, const float* __restrict__ w3root,
                                              unsigned short* __restrict__ W16) {
  int idx = blockIdx.x * 256 + threadIdx.x;  // 65536
  int k = idx >> 8, c = idx & 255;
  float v = (k < 128) ? w3rel[(size_t)k * 256 + c] : w3root[(size_t)(k - 128) * 256 + c];
  W16[(size_t)c * 256 + k] = f2bf(v);
}

// ---------------- conv3 LDS-free MFMA GEMM + fused parity pooling ----------------
// A16 [KK+1][256] bf16 row-major; W16 [256 cols][256 k] bf16 pre-transposed.
// Frags loaded directly from global; no barriers in main loop. Rows >= KK clamped (epilogue skips).
__global__ __launch_bounds__(256) void k_gemm3m(const unsigned short* __restrict__ A16,
                                                const unsigned short* __restrict__ W16,
                                                const float* __restrict__ bias,
                                                float* __restrict__ psum) {
  __shared__ float red[512];
  int t = threadIdx.x;
  int wv = t >> 6, l = t & 63;
  int n0 = blockIdx.x * 64;
  int lane16 = l & 15, kf = (l >> 4) * 8;
  f32x4 acc[4][4];
#pragma unroll
  for (int m = 0; m < 4; m++)
#pragma unroll
    for (int n = 0; n < 4; n++) acc[m][n] = (f32x4){0.f, 0.f, 0.f, 0.f};
  const unsigned short* Arow[4];
  const unsigned short* Bcol[4];
#pragma unroll
  for (int m = 0; m < 4; m++) {
    int row = min(n0 + 16 * m + lane16, KK);  // clamp; garbage rows discarded in epilogue
    Arow[m] = A16 + (size_t)row * 256 + kf;
  }
#pragma unroll
  for (int n = 0; n < 4; n++)
    Bcol[n] = W16 + (size_t)(wv * 64 + 16 * n + lane16) * 256 + kf;
#pragma unroll
  for (int k0 = 0; k0 < 256; k0 += 32) {
    bf16x8 a[4], b[4];
#pragma unroll
    for (int m = 0; m < 4; m++) a[m] = *(const bf16x8*)(Arow[m] + k0);
#pragma unroll
    for (int n = 0; n < 4; n++) b[n] = *(const bf16x8*)(Bcol[n] + k0);
#pragma unroll
    for (int m = 0; m < 4; m++)
#pragma unroll
      for (int n = 0; n < 4; n++)
        acc[m][n] = __builtin_amdgcn_mfma_f32_16x16x32_bf16(a[m], b[n], acc[m][n], 0, 0, 0);
  }
  // epilogue: rows row = n0 + 16m + (l>>4)*4 + j; col = 64wv + 16n + (l&15); parity = j&1
  for (int i = t; i < 512; i += 256) red[i] = 0.f;
  __syncthreads();
  int rbase = (l >> 4) * 4;
#pragma unroll
  for (int n = 0; n < 4; n++) {
    int col = wv * 64 + 16 * n + lane16;
    float bs = bias[col];
#pragma unroll
    for (int j = 0; j < 4; j++) {
      float s = 0.f;
#pragma unroll
      for (int m = 0; m < 4; m++) {
        int row = n0 + 16 * m + rbase + j;
        if (row < KK) s += gelu_f(acc[m][n][j] + bs);
      }
      atomicAdd(&red[(j & 1) * 256 + col], s);
    }
  }
  __syncthreads();
  for (int i = t; i < 512; i += 256) atomicAdd(&psum[i], red[i]);
}

// ---------------- final head ----------------
__global__ __launch_bounds__(512) void k_final(const float* __restrict__ psum, const float* __restrict__ wout,
                                               const float* __restrict__ bout, float* __restrict__ out) {
  __shared__ float red[512];
  int t = threadIdx.x;
  red[t] = psum[t] * (1.0f / 15000.0f) * wout[t];
  __syncthreads();
  for (int s = 256; s > 0; s >>= 1) { if (t < s) red[t] += red[t + s]; __syncthreads(); }
  if (t == 0) out[0] = red[0] + bout[0];
}

extern "C" void kernel_launch(void* const* d_in, const int* in_sizes, int n_in,
                              void* d_out, int out_size, void* d_ws, size_t ws_size,
                              hipStream_t stream) {
  const float* x      = (const float*)d_in[0];
  const int*   ei     = (const int*)d_in[1];
  const float* wdr    = (const float*)d_in[2];
  const float* wdb    = (const float*)d_in[3];
  const float* w0rel  = (const float*)d_in[4];
  const float* w0root = (const float*)d_in[5];
  const float* w0b    = (const float*)d_in[6];
  const float* w1rel  = (const float*)d_in[7];
  const float* w1root = (const float*)d_in[8];
  const float* w1b    = (const float*)d_in[9];
  const float* w2rel  = (const float*)d_in[10];
  const float* w2root = (const float*)d_in[11];
  const float* w2b    = (const float*)d_in[12];
  const float* poolp  = (const float*)d_in[13];
  const float* w3rel  = (const float*)d_in[14];
  const float* w3root = (const float*)d_in[15];
  const float* w3b    = (const float*)d_in[16];
  const float* wout   = (const float*)d_in[17];
  const float* bout   = (const float*)d_in[18];
  float* out = (float*)d_out;

  char* ws = (char*)d_ws;
  size_t o = 0;
  auto alloc = [&](size_t bytes) { size_t r = o; o += (bytes + 255) & ~(size_t)255; return r; };
  // --- zeroed block (one memset) ---
  size_t o_psum = alloc(512 * 4);
  size_t zbytes = o;
  // --- fully-written buffers ---
  size_t o_rowp = alloc((size_t)(NN + 1) * 4);
  size_t o_csr  = alloc((size_t)EE * 4);
  size_t o_h0   = alloc((size_t)NN * 4 * 4);
  size_t o_h1   = alloc((size_t)NN * 32 * 4);   // NOTE: h1+h2 region re-used as A16 after radix
  size_t o_h2   = alloc((size_t)NN * 64 * 4);   // also aliased as radix histMat after conv2
  size_t o_h3   = alloc((size_t)NN * 128 * 4);
  size_t o_agg  = alloc((size_t)NN * 64 * 4);   // also aliased as chunkEdges during CSR build
  size_t o_scor = alloc((size_t)NN * 4);
  size_t o_skey = alloc((size_t)NN * 4);
  size_t o_rank = alloc((size_t)NN * 4);
  size_t o_inv  = alloc((size_t)KK * 4);
  size_t o_keyB = alloc((size_t)NN * 4);
  size_t o_idB  = alloc((size_t)NN * 4);
  size_t o_tot  = alloc(65536 * 4);
  size_t o_bsB  = alloc(1024 * 4);
  size_t o_W16  = alloc((size_t)256 * 256 * 2);
  size_t o_W1T  = alloc((size_t)64 * 64 * 2);
  size_t o_W2T  = alloc((size_t)128 * 128 * 2);
  size_t o_cbase = alloc((size_t)GBLK * (BKT + 1) * 4);
  size_t o_bbase = alloc((size_t)(BKT + 1) * 4);
  (void)ws_size; (void)in_sizes; (void)n_in; (void)out_size;

  float*    psum = (float*)(ws + o_psum);
  int*      rowp = (int*)(ws + o_rowp);
  int*      csr  = (int*)(ws + o_csr);
  float*    h0   = (float*)(ws + o_h0);
  float*    h1   = (float*)(ws + o_h1);
  float*    h2   = (float*)(ws + o_h2);
  float*    h3   = (float*)(ws + o_h3);
  float*    agg  = (float*)(ws + o_agg);
  float*    scor = (float*)(ws + o_scor);
  unsigned* skey = (unsigned*)(ws + o_skey);
  int*      rank = (int*)(ws + o_rank);
  int*      inv  = (int*)(ws + o_inv);
  unsigned* keyB = (unsigned*)(ws + o_keyB);
  unsigned* idB  = (unsigned*)(ws + o_idB);
  unsigned* tot  = (unsigned*)(ws + o_tot);
  unsigned* bsB  = (unsigned*)(ws + o_bsB);
  unsigned* hist = (unsigned*)(ws + o_h2);            // alias: h2 dead after conv2 GEMM
  unsigned short* A16 = (unsigned short*)(ws + o_h1); // alias: h1+h2 dead after radix; (KK+1) rows fit
  unsigned short* W16 = (unsigned short*)(ws + o_W16);
  unsigned short* W1T = (unsigned short*)(ws + o_W1T);
  unsigned short* W2T = (unsigned short*)(ws + o_W2T);
  unsigned* chunkEdges = (unsigned*)(ws + o_agg);     // alias: agg unused until conv0
  int*      chunkBase  = (int*)(ws + o_cbase);
  unsigned* bktBase    = (unsigned*)(ws + o_bbase);

  hipMemsetAsync(ws, 0, zbytes, stream);

  const int* src = ei;
  const int* dstp = ei + EE;

  // CSR build (reused by all 4 convs): chunk bucket-sort -> bucket scan -> per-bucket rowp+csr
  k_binA<<<GBLK, 512, 0, stream>>>(src, dstp, chunkEdges, chunkBase);
  k_bktsum<<<1, 512, 0, stream>>>(chunkBase, bktBase);
  k_binC<<<BKT, 256, 0, stream>>>(chunkEdges, chunkBase, bktBase, rowp, csr);

  // weight pre-convert (tiny; any time before the gemms)
  k_wcvtT<32, 64><<<(64 * 64) / 256, 256, 0, stream>>>(w1rel, w1root, W1T);
  k_wcvtT<64, 128><<<(128 * 128) / 256, 256, 0, stream>>>(w2rel, w2root, W2T);
  k_wcvt<<<256, 256, 0, stream>>>(w3rel, w3root, W16);

  // dense input layer
  k_dense<<<(NN + 255) / 256, 256, 0, stream>>>(x, wdr, wdb, h0);

  // conv0: 4 -> 32
  k_agg<1><<<(NN + 255) / 256, 256, 0, stream>>>(h0, rowp, csr, agg);
  k_gemm0<<<(NN * 32 + 255) / 256, 256, 0, stream>>>(agg, h0, w0rel, w0root, w0b, h1);

  // conv1: 32 -> 64 (bf16 MFMA, LDS-free)
  k_agg<8><<<(NN * 8 + 255) / 256, 256, 0, stream>>>(h1, rowp, csr, agg);
  k_gemmM<32, 64><<<(NN + 63) / 64, 256, 0, stream>>>(agg, h1, W1T, w1b, h2, NN);

  // conv2: 64 -> 128 (bf16 MFMA, LDS-free)
  k_agg<16><<<(NN * 16 + 255) / 256, 256, 0, stream>>>(h2, rowp, csr, agg);
  k_gemmM<64, 128><<<(NN + 63) / 64, 256, 0, stream>>>(agg, h2, W2T, w2b, h3, NN);

  // score + key + fused radix pass-1 histogram (hist aliases h2: dead after conv2 GEMM)
  hipMemsetAsync(hist, 0, (size_t)NTILES * 65536 * 4, stream);
  k_score<<<(NN + 7) / 8, 256, 0, stream>>>(h3, poolp, scor, skey, hist);

  // ---- radix sort pass 1 (low 16 bits) ----
  k_rtileprefix<<<65536 / 256, 256, 0, stream>>>(hist, tot);
  k_scanA<<<64, 1024, 0, stream>>>(tot, tot, bsB, 65536);
  k_scanB<<<1, 1024, 0, stream>>>(bsB, 64);
  k_scanC<<<64, 1024, 0, stream>>>(tot, bsB, 65536);
  k_rscatter<0, true><<<NTILES, 64, 0, stream>>>(skey, nullptr, hist, tot, keyB, idB);

  // ---- radix sort pass 2 (high 16 bits), fused rank/inv write ----
  hipMemsetAsync(hist, 0, (size_t)NTILES * 65536 * 4, stream);
  k_rhist<16><<<(NN + 255) / 256, 256, 0, stream>>>(keyB, hist);
  k_rtileprefix<<<65536 / 256, 256, 0, stream>>>(hist, tot);
  k_scanA<<<64, 1024, 0, stream>>>(tot, tot, bsB, 65536);
  k_scanB<<<1, 1024, 0, stream>>>(bsB, 64);
  k_scanC<<<64, 1024, 0, stream>>>(tot, bsB, 65536);
  k_rscatter2<<<NTILES, 64, 0, stream>>>(keyB, idB, hist, tot, rank, inv);

  // conv3: 128 -> 256 on kept nodes via bf16 MFMA (LDS-free), fused parity pooling
  k_gate<<<((KK + 1) * 16 + 255) / 256, 256, 0, stream>>>(h3, scor, inv, A16);
  k_agg3<<<((long)NN * 16 + 255) / 256, 256, 0, stream>>>(rank, rowp, csr, A16);
  k_gemm3m<<<(KK + 63) / 64, 256, 0, stream>>>(A16, W16, w3b, psum);

  // head
  k_final<<<1, 512, 0, stream>>>(psum, wout, bout, out);
}